// Round 3
// baseline (6185.855 us; speedup 1.0000x reference)
//
#include <hip/hip_runtime.h>

#define Tn 512
#define Bn 64
#define In 300
#define Hn 1000
#define G4H 4000
#define KP 1024   // padded K for recurrence (H=1000 -> 1024)
#define KI 320    // padded K for input GEMM (I=300 -> 320)
#define NB 125    // scan blocks: 125 * 8 hidden cols = 1000

typedef __attribute__((ext_vector_type(8))) short bf16x8;
typedef __attribute__((ext_vector_type(4))) float f32x4;
typedef unsigned int u32;
typedef unsigned short u16;
typedef unsigned long long u64;

__device__ __forceinline__ u16 f2bf(float x) {
  union { float f; u32 u; } v; v.f = x;
  u32 r = (v.u + 0x7fffu + ((v.u >> 16) & 1u)) >> 16;
  return (u16)r;
}
__device__ __forceinline__ float bf2f(u16 s) {
  union { u32 u; float f; } v; v.u = ((u32)s) << 16;
  return v.f;
}
__device__ __forceinline__ float sigm(float x) { return 1.f / (1.f + __expf(-x)); }
__device__ __forceinline__ float tanh_f(float x) {
  float e = __expf(2.f * x);
  return 1.f - 2.f / (e + 1.f);
}

// Relaxed agent-scope accesses: routed to the coherent point per-access,
// no cache-maintenance ops.
__device__ __forceinline__ u64 aload64(const u64* p) {
  return __hip_atomic_load((u64*)p, __ATOMIC_RELAXED, __HIP_MEMORY_SCOPE_AGENT);
}
__device__ __forceinline__ void astore64(u64* p, u64 v) {
  __hip_atomic_store(p, v, __ATOMIC_RELAXED, __HIP_MEMORY_SCOPE_AGENT);
}
__device__ __forceinline__ u32 aload32(const u32* p) {
  return __hip_atomic_load((u32*)p, __ATOMIC_RELAXED, __HIP_MEMORY_SCOPE_AGENT);
}
__device__ __forceinline__ void astore32(u32* p, u32 v) {
  __hip_atomic_store(p, v, __ATOMIC_RELAXED, __HIP_MEMORY_SCOPE_AGENT);
}

// ---------------------------------------------------------------- converts
__global__ void conv_pad(const float* __restrict__ src, u16* __restrict__ dst,
                         int rows, int scols, int dcols) {
  int idx = blockIdx.x * 256 + threadIdx.x;
  int total = rows * dcols;
  if (idx >= total) return;
  int r = idx / dcols, k = idx - r * dcols;
  float v = (k < scols) ? src[(size_t)r * scols + k] : 0.f;
  dst[idx] = f2bf(v);
}

// init h double-buffer (bf16, K-padded with zeros) + zero flags area
__global__ void init_scan(const float* __restrict__ h0, u16* __restrict__ hbuf,
                          u32* __restrict__ bar) {
  int idx = blockIdx.x * 256 + threadIdx.x;
  if (idx < 4096) bar[idx] = 0;
  if (idx >= 2 * Bn * KP) return;
  int which = idx >> 16;          // 64*1024 = 65536 per buffer
  int rem = idx & 65535;
  int b = rem >> 10, k = rem & (KP - 1);
  float v = (which == 0 && k < Hn) ? h0[b * Hn + k] : 0.f;
  hbuf[idx] = f2bf(v);
}

// ---------------------------------------------------------------- xg GEMM
// Writes xg in scan-friendly layout: xg[t][nb][b][32], slot = g*8 + cc
// where hidden col j = 8*nb + cc, gate col n = g*1000 + j.
template<bool XF32>
__global__ void __launch_bounds__(256)
gemm_xg(const u16* __restrict__ A, const u16* __restrict__ Wb,
        const float* __restrict__ b_ih, const float* __restrict__ b_hh,
        void* __restrict__ xg_out) {
  const int lane = threadIdx.x & 63, w = threadIdx.x >> 6;
  const int m0 = blockIdx.x * 64, n0 = blockIdx.y * 64;
  f32x4 acc[4] = {};
  const int arow = m0 + w * 16 + (lane & 15);
  const int koff = (lane >> 4) * 8;
  int nrow[4];
#pragma unroll
  for (int nt = 0; nt < 4; ++nt) {
    int n = n0 + nt * 16 + (lane & 15);
    nrow[nt] = (n < G4H) ? n : (G4H - 1);
  }
  for (int kc = 0; kc < KI / 32; ++kc) {
    bf16x8 a = *(const bf16x8*)(A + (size_t)arow * KI + kc * 32 + koff);
#pragma unroll
    for (int nt = 0; nt < 4; ++nt) {
      bf16x8 bb = *(const bf16x8*)(Wb + (size_t)nrow[nt] * KI + kc * 32 + koff);
      acc[nt] = __builtin_amdgcn_mfma_f32_16x16x32_bf16(a, bb, acc[nt], 0, 0, 0);
    }
  }
#pragma unroll
  for (int nt = 0; nt < 4; ++nt) {
    int col = n0 + nt * 16 + (lane & 15);
    if (col >= G4H) continue;
    float bias = b_ih[col] + b_hh[col];
    u32 g = (u32)col / 1000u;
    int j = col - (int)g * 1000;
    int nb8 = j >> 3, cc = j & 7;
    int slot = ((int)g << 3) | cc;       // = jj in [0,32)
    int mrow = m0 + w * 16 + (lane >> 4) * 4;
#pragma unroll
    for (int r = 0; r < 4; ++r) {
      int m = mrow + r;
      int t = m >> 6, b = m & 63;
      float v = acc[nt][r] + bias;
      size_t o = (((size_t)t * NB + nb8) * 64 + b) * 32 + slot;
      if constexpr (XF32) ((float*)xg_out)[o] = v;
      else                ((u16*)xg_out)[o] = f2bf(v);
    }
  }
}

// ---------------------------------------------------------------- scan
// 125 blocks x 256 threads. Block nb owns hidden cols [8nb, 8nb+8).
//
// DATAFLOW SYNC with VERIFIED flags:
//  - Producer: stores h(t+1) via L2-bypassing u64 stores, then each storing
//    thread RE-LOADS its own u64 (same bypass path) and spins until it reads
//    back the stored value. A successful readback proves the data is
//    physically at the coherent point (L3) -- no reliance on store-ack
//    semantics. Only then does tid0 publish flag[nb] = t+1.
//  - Consumer: K range [0,1024) = 4 groups of 8 kc; group g produced by
//    blocks [32g, 32g+32). Wave w polls group w's 32 flags (4 concurrent
//    polls across waves), publishes lready[w]=t in LDS; loads/MFMAs per
//    group are gated on lready and stream in as producers land.
//  - Write-safety (no counter needed): producer at step t overwrites parity
//    (t+1)&1, which holds h(t-1). It reached step t only after observing ALL
//    flags >= t; flag_X >= t is published only after block X finished its
//    step-(t-1) MFMAs, whose h(t-1) loads were already bound into registers.
//    Hence no read of h(t-1) can still be in flight anywhere. Readers of the
//    same parity as h(t+1) wait for flags >= t+1, published after the
//    verified stores. Max skew between blocks is 1 step; no deadlock (a
//    block's own flag is already >= t when it polls).
template<bool XF32>
__global__ void __launch_bounds__(256, 1)
lstm_scan(const float* __restrict__ Whh, const float* __restrict__ c0,
          const void* __restrict__ xg_, u64* __restrict__ hbu,
          float* __restrict__ out, u32* __restrict__ bar) {
  __shared__ float Sc[4][16][33];
  __shared__ __align__(8) u16 hs[64][8];
  __shared__ int lready[4];
  const int tid = threadIdx.x;
  const int lane = tid & 63;
  const int w = tid >> 6;
  const int nb = blockIdx.x;
  const int s = lane & 15;        // gate-row index within N-tile
  const int q = lane >> 4;        // k-quarter

  if (tid < 4) lready[tid] = 0;

  u32* flags = bar + 256;   // per-block data-ready flags (monotonic step tags)

  // ---- stage this lane's W_hh B-fragments for 2 N-tiles (once) ----
  bf16x8 wreg0[32], wreg1[32];
  {
    const int jj0 = s;
    const float* wrow0 =
        Whh + (size_t)((jj0 >> 3) * Hn + nb * 8 + (jj0 & 7)) * Hn;
    const int jj1 = 16 + s;
    const float* wrow1 =
        Whh + (size_t)((jj1 >> 3) * Hn + nb * 8 + (jj1 & 7)) * Hn;
#pragma unroll
    for (int kc = 0; kc < 32; ++kc) {
      const int k0 = kc * 32 + q * 8;
      bf16x8 v0, v1;
#pragma unroll
      for (int j = 0; j < 8; ++j) {
        float f0 = (k0 + j < Hn) ? wrow0[k0 + j] : 0.f;
        float f1 = (k0 + j < Hn) ? wrow1[k0 + j] : 0.f;
        v0[j] = (short)f2bf(f0);
        v1[j] = (short)f2bf(f1);
      }
      wreg0[kc] = v0;
      wreg1[kc] = v1;
    }
  }

  // elementwise lane mapping: 2 cells per lane: (batch-local bl+8k, col cc)
  const int bl = lane >> 3, cc = lane & 7;
  const int jh = nb * 8 + cc;
  float cst[2];
  cst[0] = c0[(size_t)(w * 16 + bl) * Hn + jh];
  cst[1] = c0[(size_t)(w * 16 + bl + 8) * Hn + jh];

  const float* xf = (const float*)xg_;
  const u16* xh = (const u16*)xg_;

  // prefetch xg for t=0
  float xa[8];
  {
    size_t base = (((size_t)0 * NB + nb) * 64 + w * 16 + q * 4) * 32 + s;
#pragma unroll
    for (int nt = 0; nt < 2; ++nt)
#pragma unroll
      for (int r = 0; r < 4; ++r) {
        size_t o = base + (size_t)r * 32 + nt * 16;
        xa[nt * 4 + r] = XF32 ? xf[o] : bf2f(xh[o]);
      }
  }

  // my flag index to poll (wave w polls producers of K-group w)
  int pidx = 32 * w + (lane & 31);
  if (pidx >= NB) pidx = NB - 1;

  __syncthreads();   // lready init visible

  union U { u64 d[2]; bf16x8 v; };

  // u64 geometry: one h buffer = Bn*KP/4 = 16384 u64; row stride 256 u64.
  for (int t = 0; t < Tn; ++t) {
    const u64* hc = hbu + (size_t)(t & 1) * 16384;
    u64* hn = hbu + (size_t)((t + 1) & 1) * 16384;
    const u64* hrow = hc + (size_t)(w * 16 + s) * 256 + q * 2;

    // ---- duty poll: wave w waits for group-w producers, publishes to LDS
    if (t > 0) {
      while (true) {
        u32 f = aload32(flags + pidx);
        if (__all((int)(f >= (u32)t))) break;
        __builtin_amdgcn_s_sleep(2);
      }
      if (lane == 0)
        __hip_atomic_store(&lready[w], t, __ATOMIC_RELAXED,
                           __HIP_MEMORY_SCOPE_WORKGROUP);
    }

    auto wait_g = [&](int g) {
      if (g == w) return;
      while (__hip_atomic_load(&lready[g], __ATOMIC_RELAXED,
                               __HIP_MEMORY_SCOPE_WORKGROUP) < t) {
      }
      __builtin_amdgcn_sched_barrier(0);
    };
    auto load8 = [&](U* buf, int kcb) {
#pragma unroll
      for (int k = 0; k < 8; ++k) {
        buf[k].d[0] = aload64(hrow + (kcb + k) * 8);
        buf[k].d[1] = aload64(hrow + (kcb + k) * 8 + 1);
      }
    };

    f32x4 a00 = {xa[0], xa[1], xa[2], xa[3]};
    f32x4 a01 = {0.f, 0.f, 0.f, 0.f};
    f32x4 a10 = {xa[4], xa[5], xa[6], xa[7]};
    f32x4 a11 = {0.f, 0.f, 0.f, 0.f};

    U b0[8], b1[8];
    wait_g(0);
    load8(b0, 0);
    wait_g(1);
    load8(b1, 8);
#pragma unroll
    for (int k = 0; k < 8; ++k) {
      a00 = __builtin_amdgcn_mfma_f32_16x16x32_bf16(b0[k].v, wreg0[k], a00, 0, 0, 0);
      a10 = __builtin_amdgcn_mfma_f32_16x16x32_bf16(b0[k].v, wreg1[k], a10, 0, 0, 0);
    }
    wait_g(2);
    load8(b0, 16);
#pragma unroll
    for (int k = 0; k < 8; ++k) {
      a00 = __builtin_amdgcn_mfma_f32_16x16x32_bf16(b1[k].v, wreg0[8 + k], a00, 0, 0, 0);
      a10 = __builtin_amdgcn_mfma_f32_16x16x32_bf16(b1[k].v, wreg1[8 + k], a10, 0, 0, 0);
    }
    wait_g(3);
    load8(b1, 24);
#pragma unroll
    for (int k = 0; k < 8; ++k) {
      a01 = __builtin_amdgcn_mfma_f32_16x16x32_bf16(b0[k].v, wreg0[16 + k], a01, 0, 0, 0);
      a11 = __builtin_amdgcn_mfma_f32_16x16x32_bf16(b0[k].v, wreg1[16 + k], a11, 0, 0, 0);
    }
#pragma unroll
    for (int k = 0; k < 8; ++k) {
      a01 = __builtin_amdgcn_mfma_f32_16x16x32_bf16(b1[k].v, wreg0[24 + k], a01, 0, 0, 0);
      a11 = __builtin_amdgcn_mfma_f32_16x16x32_bf16(b1[k].v, wreg1[24 + k], a11, 0, 0, 0);
    }

    // redistribute C within the wave via LDS (writer wave == reader wave)
#pragma unroll
    for (int r = 0; r < 4; ++r) {
      Sc[w][q * 4 + r][s]      = a00[r] + a01[r];
      Sc[w][q * 4 + r][16 + s] = a10[r] + a11[r];
    }

    float hv[2];
#pragma unroll
    for (int k = 0; k < 2; ++k) {
      int bb = bl + 8 * k;
      float gi = Sc[w][bb][cc];
      float gf = Sc[w][bb][8 + cc];
      float gg = Sc[w][bb][16 + cc];
      float go = Sc[w][bb][24 + cc];
      float iv = sigm(gi), fv = sigm(gf), gv = tanh_f(gg), ov = sigm(go);
      cst[k] = fv * cst[k] + iv * gv;
      hv[k] = ov * tanh_f(cst[k]);
      out[((size_t)t * Bn + (w * 16 + bb)) * Hn + jh] = hv[k];  // cached store
      hs[w * 16 + bb][cc] = f2bf(hv[k]);                        // stage bf16
    }

    if (t != Tn - 1) {
      __syncthreads();                 // hs ready; block's MFMAs done
      if (tid < 128) {
        int row = tid >> 1, half = tid & 1;
        u64 hvv = *(const u64*)&hs[row][half * 4];   // 4 bf16 packed
        u64* ad = hn + (size_t)row * 256 + nb * 2 + half;
        astore64(ad, hvv);
        // readback-verify: loop until the bypass load returns what we
        // stored -> data is physically at the coherent point.
        while (aload64(ad) != hvv) __builtin_amdgcn_s_sleep(1);
      }
      __syncthreads();                 // all 128 stores verified at L3
      if (tid == 0) astore32(flags + nb, (u32)(t + 1));  // publish ready

      // next-step xg prefetch (normal cached loads, overlaps next poll)
      {
        size_t base =
            (((size_t)(t + 1) * NB + nb) * 64 + w * 16 + q * 4) * 32 + s;
#pragma unroll
        for (int nt = 0; nt < 2; ++nt)
#pragma unroll
          for (int r = 0; r < 4; ++r) {
            size_t o = base + (size_t)r * 32 + nt * 16;
            xa[nt * 4 + r] = XF32 ? xf[o] : bf2f(xh[o]);
          }
      }
    }
  }
}

// ---------------------------------------------------------------- launch
extern "C" void kernel_launch(void* const* d_in, const int* in_sizes, int n_in,
                              void* d_out, int out_size, void* d_ws, size_t ws_size,
                              hipStream_t stream) {
  const float* inputs = (const float*)d_in[0];
  const float* h0 = (const float*)d_in[1];
  const float* c0 = (const float*)d_in[2];
  const float* W_ih = (const float*)d_in[3];
  const float* W_hh = (const float*)d_in[4];
  const float* b_ih = (const float*)d_in[5];
  const float* b_hh = (const float*)d_in[6];
  float* out = (float*)d_out;

  char* ws = (char*)d_ws;
  size_t off = 0;
  auto carve = [&](size_t bytes) {
    char* p = ws + off;
    off = (off + bytes + 255) & ~(size_t)255;
    return p;
  };
  u32* bar = (u32*)carve(16384);
  u16* in_bf = (u16*)carve((size_t)Tn * Bn * KI * 2);
  u16* wih_bf = (u16*)carve((size_t)G4H * KI * 2);
  u16* hbuf = (u16*)carve((size_t)2 * Bn * KP * 2);
  size_t fixed = off;
  size_t xg_f32 = (size_t)Tn * NB * 64 * 32 * 4;
  bool xf32 = (ws_size >= fixed + xg_f32);
  void* xg = (void*)carve(xf32 ? xg_f32 : xg_f32 / 2);

  int tot_in = Tn * Bn * KI;
  conv_pad<<<dim3((tot_in + 255) / 256), dim3(256), 0, stream>>>(
      inputs, in_bf, Tn * Bn, In, KI);
  int tot_w = G4H * KI;
  conv_pad<<<dim3((tot_w + 255) / 256), dim3(256), 0, stream>>>(
      W_ih, wih_bf, G4H, In, KI);
  init_scan<<<dim3(512), dim3(256), 0, stream>>>(h0, hbuf, bar);

  if (xf32) {
    gemm_xg<true><<<dim3(Tn * Bn / 64, (G4H + 63) / 64), dim3(256), 0, stream>>>(
        in_bf, wih_bf, b_ih, b_hh, xg);
    lstm_scan<true><<<dim3(NB), dim3(256), 0, stream>>>(
        W_hh, c0, xg, (u64*)hbuf, out, bar);
  } else {
    gemm_xg<false><<<dim3(Tn * Bn / 64, (G4H + 63) / 64), dim3(256), 0, stream>>>(
        in_bf, wih_bf, b_ih, b_hh, xg);
    lstm_scan<false><<<dim3(NB), dim3(256), 0, stream>>>(
        W_hh, c0, xg, (u64*)hbuf, out, bar);
  }
}

// Round 4
// 4618.504 us; speedup vs baseline: 1.3394x; 1.3394x over previous
//
#include <hip/hip_runtime.h>

#define Tn 512
#define Bn 64
#define In 300
#define Hn 1000
#define G4H 4000
#define KP 1024   // padded K for recurrence (H=1000 -> 1024)
#define KI 320    // padded K for input GEMM (I=300 -> 320)
#define NB 125    // scan blocks: 125 * 8 hidden cols = 1000

typedef __attribute__((ext_vector_type(8))) short bf16x8;
typedef __attribute__((ext_vector_type(4))) float f32x4;
typedef unsigned int u32;
typedef unsigned short u16;
typedef unsigned long long u64;

__device__ __forceinline__ u16 f2bf(float x) {
  union { float f; u32 u; } v; v.f = x;
  u32 r = (v.u + 0x7fffu + ((v.u >> 16) & 1u)) >> 16;
  return (u16)r;
}
__device__ __forceinline__ float bf2f(u16 s) {
  union { u32 u; float f; } v; v.u = ((u32)s) << 16;
  return v.f;
}
__device__ __forceinline__ float sigm(float x) { return 1.f / (1.f + __expf(-x)); }
__device__ __forceinline__ float tanh_f(float x) {
  float e = __expf(2.f * x);
  return 1.f - 2.f / (e + 1.f);
}

// Relaxed agent-scope accesses: routed to the coherent point per-access.
// Used ONLY for the producer-side h stores + readback-verify and the flags.
// The h READ path is plain cached loads from a write-once ring (see below).
__device__ __forceinline__ u64 aload64(const u64* p) {
  return __hip_atomic_load((u64*)p, __ATOMIC_RELAXED, __HIP_MEMORY_SCOPE_AGENT);
}
__device__ __forceinline__ void astore64(u64* p, u64 v) {
  __hip_atomic_store(p, v, __ATOMIC_RELAXED, __HIP_MEMORY_SCOPE_AGENT);
}
__device__ __forceinline__ u32 aload32(const u32* p) {
  return __hip_atomic_load((u32*)p, __ATOMIC_RELAXED, __HIP_MEMORY_SCOPE_AGENT);
}
__device__ __forceinline__ void astore32(u32* p, u32 v) {
  __hip_atomic_store(p, v, __ATOMIC_RELAXED, __HIP_MEMORY_SCOPE_AGENT);
}

// ---------------------------------------------------------------- converts
__global__ void conv_pad(const float* __restrict__ src, u16* __restrict__ dst,
                         int rows, int scols, int dcols) {
  int idx = blockIdx.x * 256 + threadIdx.x;
  int total = rows * dcols;
  if (idx >= total) return;
  int r = idx / dcols, k = idx - r * dcols;
  float v = (k < scols) ? src[(size_t)r * scols + k] : 0.f;
  dst[idx] = f2bf(v);
}

// init: zero flags; write h(0) into ring slot 0; zero the K-pad cols
// (1000..1023) of ALL later slots (they are never written by producers and
// feed MFMAs against zero weights -- must not contain NaN garbage).
// Plain cached stores are safe here: dispatch-completion performs the
// implicit device-scope release (L2 writeback+inv), so lstm_scan starts
// with this data at the coherent point and no stale L2 copies anywhere.
__global__ void init_scan(const float* __restrict__ h0, u16* __restrict__ ring,
                          u32* __restrict__ bar) {
  int idx = blockIdx.x * 256 + threadIdx.x;   // grid: 512*256 = 131072
  if (idx < 4096) bar[idx] = 0;
  if (idx < Bn * KP) {
    int b = idx >> 10, k = idx & (KP - 1);
    float v = (k < Hn) ? h0[b * Hn + k] : 0.f;
    ring[idx] = f2bf(v);
  }
  for (int i = idx; i < (Tn - 1) * Bn * 24; i += 512 * 256) {
    int slot = 1 + i / (Bn * 24);
    int rem = i % (Bn * 24);
    int row = rem / 24, col = 1000 + (rem % 24);
    ring[(size_t)slot * (Bn * KP) + (size_t)row * KP + col] = 0;
  }
}

// ---------------------------------------------------------------- xg GEMM
// Writes xg in scan-friendly layout: xg[t][nb][b][32], slot = g*8 + cc
// where hidden col j = 8*nb + cc, gate col n = g*1000 + j.
template<bool XF32>
__global__ void __launch_bounds__(256)
gemm_xg(const u16* __restrict__ A, const u16* __restrict__ Wb,
        const float* __restrict__ b_ih, const float* __restrict__ b_hh,
        void* __restrict__ xg_out) {
  const int lane = threadIdx.x & 63, w = threadIdx.x >> 6;
  const int m0 = blockIdx.x * 64, n0 = blockIdx.y * 64;
  f32x4 acc[4] = {};
  const int arow = m0 + w * 16 + (lane & 15);
  const int koff = (lane >> 4) * 8;
  int nrow[4];
#pragma unroll
  for (int nt = 0; nt < 4; ++nt) {
    int n = n0 + nt * 16 + (lane & 15);
    nrow[nt] = (n < G4H) ? n : (G4H - 1);
  }
  for (int kc = 0; kc < KI / 32; ++kc) {
    bf16x8 a = *(const bf16x8*)(A + (size_t)arow * KI + kc * 32 + koff);
#pragma unroll
    for (int nt = 0; nt < 4; ++nt) {
      bf16x8 bb = *(const bf16x8*)(Wb + (size_t)nrow[nt] * KI + kc * 32 + koff);
      acc[nt] = __builtin_amdgcn_mfma_f32_16x16x32_bf16(a, bb, acc[nt], 0, 0, 0);
    }
  }
#pragma unroll
  for (int nt = 0; nt < 4; ++nt) {
    int col = n0 + nt * 16 + (lane & 15);
    if (col >= G4H) continue;
    float bias = b_ih[col] + b_hh[col];
    u32 g = (u32)col / 1000u;
    int j = col - (int)g * 1000;
    int nb8 = j >> 3, cc = j & 7;
    int slot = ((int)g << 3) | cc;       // = jj in [0,32)
    int mrow = m0 + w * 16 + (lane >> 4) * 4;
#pragma unroll
    for (int r = 0; r < 4; ++r) {
      int m = mrow + r;
      int t = m >> 6, b = m & 63;
      float v = acc[nt][r] + bias;
      size_t o = (((size_t)t * NB + nb8) * 64 + b) * 32 + slot;
      if constexpr (XF32) ((float*)xg_out)[o] = v;
      else                ((u16*)xg_out)[o] = f2bf(v);
    }
  }
}

// ---------------------------------------------------------------- scan
// 125 blocks x 256 threads. Block nb owns hidden cols [8nb, 8nb+8).
//
// h EXCHANGE via WRITE-ONCE RING (the round-3 floor was per-CU issue cost
// of line-divergent uncached 8B loads -- ~16K fabric transactions/CU/step):
//  - Ring: 512 slots x (64 x 1024 bf16) = 64 MB. Slot t holds h(t).
//    Every address is written exactly once -> consumers may use PLAIN
//    CACHED 16B loads (coalesced; L2-shared across the XCD) with no
//    staleness hazard and no overwrite gating at all.
//  - Producer: astore64 (L2-bypass) h(t+1) into slot t+1, then each storing
//    thread readback-verifies its own u64 via aload64 (proves data is
//    physically at the coherent point; round-2 showed store-ack is NOT
//    visibility). Then tid0 publishes flag[nb] = t+1.
//  - Consumer: K range [0,1024) = 4 groups of 8 kc; group g produced by
//    blocks [32g, 32g+32). Wave w polls group w's 32 flags, publishes
//    lready[w]=t in LDS; loads/MFMAs per group stream in as producers land.
//    Flag groups are 256-col = 64B-line aligned, so no loaded line can have
//    a concurrent un-flagged writer.
template<bool XF32>
__global__ void __launch_bounds__(256, 1)
lstm_scan(const float* __restrict__ Whh, const float* __restrict__ c0,
          const void* __restrict__ xg_, u16* __restrict__ ring,
          float* __restrict__ out, u32* __restrict__ bar) {
  __shared__ float Sc[4][16][33];
  __shared__ __align__(8) u16 hs[64][8];
  __shared__ int lready[4];
  const int tid = threadIdx.x;
  const int lane = tid & 63;
  const int w = tid >> 6;
  const int nb = blockIdx.x;
  const int s = lane & 15;        // gate-row index within N-tile
  const int q = lane >> 4;        // k-quarter

  if (tid < 4) lready[tid] = 0;

  u32* flags = bar + 256;   // per-block data-ready flags (monotonic step tags)
  u64* ring64 = (u64*)ring;

  // ---- stage this lane's W_hh B-fragments for 2 N-tiles (once) ----
  bf16x8 wreg0[32], wreg1[32];
  {
    const int jj0 = s;
    const float* wrow0 =
        Whh + (size_t)((jj0 >> 3) * Hn + nb * 8 + (jj0 & 7)) * Hn;
    const int jj1 = 16 + s;
    const float* wrow1 =
        Whh + (size_t)((jj1 >> 3) * Hn + nb * 8 + (jj1 & 7)) * Hn;
#pragma unroll
    for (int kc = 0; kc < 32; ++kc) {
      const int k0 = kc * 32 + q * 8;
      bf16x8 v0, v1;
#pragma unroll
      for (int j = 0; j < 8; ++j) {
        float f0 = (k0 + j < Hn) ? wrow0[k0 + j] : 0.f;
        float f1 = (k0 + j < Hn) ? wrow1[k0 + j] : 0.f;
        v0[j] = (short)f2bf(f0);
        v1[j] = (short)f2bf(f1);
      }
      wreg0[kc] = v0;
      wreg1[kc] = v1;
    }
  }

  // elementwise lane mapping: 2 cells per lane: (batch-local bl+8k, col cc)
  const int bl = lane >> 3, cc = lane & 7;
  const int jh = nb * 8 + cc;
  float cst[2];
  cst[0] = c0[(size_t)(w * 16 + bl) * Hn + jh];
  cst[1] = c0[(size_t)(w * 16 + bl + 8) * Hn + jh];

  const float* xf = (const float*)xg_;
  const u16* xh = (const u16*)xg_;

  // prefetch xg for t=0
  float xa[8];
  {
    size_t base = (((size_t)0 * NB + nb) * 64 + w * 16 + q * 4) * 32 + s;
#pragma unroll
    for (int nt = 0; nt < 2; ++nt)
#pragma unroll
      for (int r = 0; r < 4; ++r) {
        size_t o = base + (size_t)r * 32 + nt * 16;
        xa[nt * 4 + r] = XF32 ? xf[o] : bf2f(xh[o]);
      }
  }

  // my flag index to poll (wave w polls producers of K-group w)
  int pidx = 32 * w + (lane & 31);
  if (pidx >= NB) pidx = NB - 1;

  __syncthreads();   // lready init visible

  for (int t = 0; t < Tn; ++t) {
    // slot t: consumer reads h(t) with plain cached loads
    const u16* hrow = ring + (size_t)t * (Bn * KP) +
                      (size_t)(w * 16 + s) * KP + q * 8;
    // slot t+1: producer writes h(t+1) (u64 view; row stride 256 u64)
    u64* hn = ring64 + (size_t)(t + 1) * (Bn * KP / 4);

    // ---- duty poll: wave w waits for group-w producers, publishes to LDS
    if (t > 0) {
      while (true) {
        u32 f = aload32(flags + pidx);
        if (__all((int)(f >= (u32)t))) break;
        __builtin_amdgcn_s_sleep(2);
      }
      if (lane == 0)
        __hip_atomic_store(&lready[w], t, __ATOMIC_RELAXED,
                           __HIP_MEMORY_SCOPE_WORKGROUP);
    }

    auto wait_g = [&](int g) {
      if (g == w) return;
      while (__hip_atomic_load(&lready[g], __ATOMIC_RELAXED,
                               __HIP_MEMORY_SCOPE_WORKGROUP) < t) {
      }
      __builtin_amdgcn_sched_barrier(0);
    };
    auto load8 = [&](bf16x8* buf, int kcb) {
#pragma unroll
      for (int k = 0; k < 8; ++k)
        buf[k] = *(const bf16x8*)(hrow + (size_t)(kcb + k) * 32);
    };

    f32x4 a00 = {xa[0], xa[1], xa[2], xa[3]};
    f32x4 a01 = {0.f, 0.f, 0.f, 0.f};
    f32x4 a10 = {xa[4], xa[5], xa[6], xa[7]};
    f32x4 a11 = {0.f, 0.f, 0.f, 0.f};

    bf16x8 b0[8], b1[8];
    wait_g(0);
    load8(b0, 0);
    wait_g(1);
    load8(b1, 8);
#pragma unroll
    for (int k = 0; k < 8; ++k) {
      a00 = __builtin_amdgcn_mfma_f32_16x16x32_bf16(b0[k], wreg0[k], a00, 0, 0, 0);
      a10 = __builtin_amdgcn_mfma_f32_16x16x32_bf16(b0[k], wreg1[k], a10, 0, 0, 0);
    }
    wait_g(2);
    load8(b0, 16);
#pragma unroll
    for (int k = 0; k < 8; ++k) {
      a00 = __builtin_amdgcn_mfma_f32_16x16x32_bf16(b1[k], wreg0[8 + k], a00, 0, 0, 0);
      a10 = __builtin_amdgcn_mfma_f32_16x16x32_bf16(b1[k], wreg1[8 + k], a10, 0, 0, 0);
    }
    wait_g(3);
    load8(b1, 24);
#pragma unroll
    for (int k = 0; k < 8; ++k) {
      a01 = __builtin_amdgcn_mfma_f32_16x16x32_bf16(b0[k], wreg0[16 + k], a01, 0, 0, 0);
      a11 = __builtin_amdgcn_mfma_f32_16x16x32_bf16(b0[k], wreg1[16 + k], a11, 0, 0, 0);
    }
#pragma unroll
    for (int k = 0; k < 8; ++k) {
      a01 = __builtin_amdgcn_mfma_f32_16x16x32_bf16(b1[k], wreg0[24 + k], a01, 0, 0, 0);
      a11 = __builtin_amdgcn_mfma_f32_16x16x32_bf16(b1[k], wreg1[24 + k], a11, 0, 0, 0);
    }

    // redistribute C within the wave via LDS (writer wave == reader wave)
#pragma unroll
    for (int r = 0; r < 4; ++r) {
      Sc[w][q * 4 + r][s]      = a00[r] + a01[r];
      Sc[w][q * 4 + r][16 + s] = a10[r] + a11[r];
    }

    float hv[2];
#pragma unroll
    for (int k = 0; k < 2; ++k) {
      int bb = bl + 8 * k;
      float gi = Sc[w][bb][cc];
      float gf = Sc[w][bb][8 + cc];
      float gg = Sc[w][bb][16 + cc];
      float go = Sc[w][bb][24 + cc];
      float iv = sigm(gi), fv = sigm(gf), gv = tanh_f(gg), ov = sigm(go);
      cst[k] = fv * cst[k] + iv * gv;
      hv[k] = ov * tanh_f(cst[k]);
      out[((size_t)t * Bn + (w * 16 + bb)) * Hn + jh] = hv[k];  // cached store
      hs[w * 16 + bb][cc] = f2bf(hv[k]);                        // stage bf16
    }

    if (t != Tn - 1) {
      __syncthreads();                 // hs ready; block's MFMAs done
      if (tid < 128) {
        int row = tid >> 1, half = tid & 1;
        u64 hvv = *(const u64*)&hs[row][half * 4];   // 4 bf16 packed
        u64* ad = hn + (size_t)row * 256 + nb * 2 + half;
        astore64(ad, hvv);
        // readback-verify: loop until the bypass load returns what we
        // stored -> data is physically at the coherent point.
        while (aload64(ad) != hvv) __builtin_amdgcn_s_sleep(1);
      }
      __syncthreads();                 // all 128 stores verified at L3
      if (tid == 0) astore32(flags + nb, (u32)(t + 1));  // publish ready

      // next-step xg prefetch (normal cached loads, overlaps next poll)
      {
        size_t base =
            (((size_t)(t + 1) * NB + nb) * 64 + w * 16 + q * 4) * 32 + s;
#pragma unroll
        for (int nt = 0; nt < 2; ++nt)
#pragma unroll
          for (int r = 0; r < 4; ++r) {
            size_t o = base + (size_t)r * 32 + nt * 16;
            xa[nt * 4 + r] = XF32 ? xf[o] : bf2f(xh[o]);
          }
      }
    }
  }
}

// ---------------------------------------------------------------- launch
extern "C" void kernel_launch(void* const* d_in, const int* in_sizes, int n_in,
                              void* d_out, int out_size, void* d_ws, size_t ws_size,
                              hipStream_t stream) {
  const float* inputs = (const float*)d_in[0];
  const float* h0 = (const float*)d_in[1];
  const float* c0 = (const float*)d_in[2];
  const float* W_ih = (const float*)d_in[3];
  const float* W_hh = (const float*)d_in[4];
  const float* b_ih = (const float*)d_in[5];
  const float* b_hh = (const float*)d_in[6];
  float* out = (float*)d_out;

  char* ws = (char*)d_ws;
  size_t off = 0;
  auto carve = [&](size_t bytes) {
    char* p = ws + off;
    off = (off + bytes + 255) & ~(size_t)255;
    return p;
  };
  u32* bar = (u32*)carve(16384);
  u16* in_bf = (u16*)carve((size_t)Tn * Bn * KI * 2);
  u16* wih_bf = (u16*)carve((size_t)G4H * KI * 2);
  u16* ring = (u16*)carve((size_t)Tn * Bn * KP * 2);   // 64 MB write-once ring
  size_t fixed = off;
  size_t xg_f32 = (size_t)Tn * NB * 64 * 32 * 4;
  bool xf32 = (ws_size >= fixed + xg_f32);
  void* xg = (void*)carve(xf32 ? xg_f32 : xg_f32 / 2);

  int tot_in = Tn * Bn * KI;
  conv_pad<<<dim3((tot_in + 255) / 256), dim3(256), 0, stream>>>(
      inputs, in_bf, Tn * Bn, In, KI);
  int tot_w = G4H * KI;
  conv_pad<<<dim3((tot_w + 255) / 256), dim3(256), 0, stream>>>(
      W_ih, wih_bf, G4H, In, KI);
  init_scan<<<dim3(512), dim3(256), 0, stream>>>(h0, ring, bar);

  if (xf32) {
    gemm_xg<true><<<dim3(Tn * Bn / 64, (G4H + 63) / 64), dim3(256), 0, stream>>>(
        in_bf, wih_bf, b_ih, b_hh, xg);
    lstm_scan<true><<<dim3(NB), dim3(256), 0, stream>>>(
        W_hh, c0, xg, ring, out, bar);
  } else {
    gemm_xg<false><<<dim3(Tn * Bn / 64, (G4H + 63) / 64), dim3(256), 0, stream>>>(
        in_bf, wih_bf, b_ih, b_hh, xg);
    lstm_scan<false><<<dim3(NB), dim3(256), 0, stream>>>(
        W_hh, c0, xg, ring, out, bar);
  }
}

// Round 5
// 4091.493 us; speedup vs baseline: 1.5119x; 1.1288x over previous
//
#include <hip/hip_runtime.h>

#define Tn 512
#define Bn 64
#define In 300
#define Hn 1000
#define G4H 4000
#define KP 1024   // padded K for recurrence (H=1000 -> 1024)
#define KI 320    // padded K for input GEMM (I=300 -> 320)
#define NB 125    // scan blocks: 125 * 8 hidden cols = 1000

typedef __attribute__((ext_vector_type(8))) short bf16x8;
typedef __attribute__((ext_vector_type(4))) float f32x4;
typedef unsigned int u32;
typedef unsigned short u16;
typedef unsigned long long u64;

__device__ __forceinline__ u16 f2bf(float x) {
  union { float f; u32 u; } v; v.f = x;
  u32 r = (v.u + 0x7fffu + ((v.u >> 16) & 1u)) >> 16;
  return (u16)r;
}
__device__ __forceinline__ float bf2f(u16 s) {
  union { u32 u; float f; } v; v.u = ((u32)s) << 16;
  return v.f;
}
__device__ __forceinline__ float sigm(float x) { return 1.f / (1.f + __expf(-x)); }
__device__ __forceinline__ float tanh_f(float x) {
  float e = __expf(2.f * x);
  return 1.f - 2.f / (e + 1.f);
}

// Relaxed agent-scope accesses: routed to the coherent point per-access.
// Used ONLY for the producer-side h stores + readback-verify and the flags.
// The h READ path is plain cached loads from a write-once ring.
__device__ __forceinline__ u64 aload64(const u64* p) {
  return __hip_atomic_load((u64*)p, __ATOMIC_RELAXED, __HIP_MEMORY_SCOPE_AGENT);
}
__device__ __forceinline__ void astore64(u64* p, u64 v) {
  __hip_atomic_store(p, v, __ATOMIC_RELAXED, __HIP_MEMORY_SCOPE_AGENT);
}
__device__ __forceinline__ u32 aload32(const u32* p) {
  return __hip_atomic_load((u32*)p, __ATOMIC_RELAXED, __HIP_MEMORY_SCOPE_AGENT);
}
__device__ __forceinline__ void astore32(u32* p, u32 v) {
  __hip_atomic_store(p, v, __ATOMIC_RELAXED, __HIP_MEMORY_SCOPE_AGENT);
}

// ---------------------------------------------------------------- converts
__global__ void conv_pad(const float* __restrict__ src, u16* __restrict__ dst,
                         int rows, int scols, int dcols) {
  int idx = blockIdx.x * 256 + threadIdx.x;
  int total = rows * dcols;
  if (idx >= total) return;
  int r = idx / dcols, k = idx - r * dcols;
  float v = (k < scols) ? src[(size_t)r * scols + k] : 0.f;
  dst[idx] = f2bf(v);
}

// init: zero flags; write h(0) into ring slot 0; zero the K-pad cols
// (1000..1023) of ALL later slots (they are never written by producers and
// feed MFMAs against zero weights -- must not contain NaN garbage).
__global__ void init_scan(const float* __restrict__ h0, u16* __restrict__ ring,
                          u32* __restrict__ bar) {
  int idx = blockIdx.x * 256 + threadIdx.x;   // grid: 512*256 = 131072
  if (idx < 4096) bar[idx] = 0;
  if (idx < Bn * KP) {
    int b = idx >> 10, k = idx & (KP - 1);
    float v = (k < Hn) ? h0[b * Hn + k] : 0.f;
    ring[idx] = f2bf(v);
  }
  for (int i = idx; i < (Tn - 1) * Bn * 24; i += 512 * 256) {
    int slot = 1 + i / (Bn * 24);
    int rem = i % (Bn * 24);
    int row = rem / 24, col = 1000 + (rem % 24);
    ring[(size_t)slot * (Bn * KP) + (size_t)row * KP + col] = 0;
  }
}

// ---------------------------------------------------------------- xg GEMM
// Writes xg in scan-friendly layout: xg[t][nb][b][32], slot = g*8 + cc
// where hidden col j = 8*nb + cc, gate col n = g*1000 + j.
template<bool XF32>
__global__ void __launch_bounds__(256)
gemm_xg(const u16* __restrict__ A, const u16* __restrict__ Wb,
        const float* __restrict__ b_ih, const float* __restrict__ b_hh,
        void* __restrict__ xg_out) {
  const int lane = threadIdx.x & 63, w = threadIdx.x >> 6;
  const int m0 = blockIdx.x * 64, n0 = blockIdx.y * 64;
  f32x4 acc[4] = {};
  const int arow = m0 + w * 16 + (lane & 15);
  const int koff = (lane >> 4) * 8;
  int nrow[4];
#pragma unroll
  for (int nt = 0; nt < 4; ++nt) {
    int n = n0 + nt * 16 + (lane & 15);
    nrow[nt] = (n < G4H) ? n : (G4H - 1);
  }
  for (int kc = 0; kc < KI / 32; ++kc) {
    bf16x8 a = *(const bf16x8*)(A + (size_t)arow * KI + kc * 32 + koff);
#pragma unroll
    for (int nt = 0; nt < 4; ++nt) {
      bf16x8 bb = *(const bf16x8*)(Wb + (size_t)nrow[nt] * KI + kc * 32 + koff);
      acc[nt] = __builtin_amdgcn_mfma_f32_16x16x32_bf16(a, bb, acc[nt], 0, 0, 0);
    }
  }
#pragma unroll
  for (int nt = 0; nt < 4; ++nt) {
    int col = n0 + nt * 16 + (lane & 15);
    if (col >= G4H) continue;
    float bias = b_ih[col] + b_hh[col];
    u32 g = (u32)col / 1000u;
    int j = col - (int)g * 1000;
    int nb8 = j >> 3, cc = j & 7;
    int slot = ((int)g << 3) | cc;       // = jj in [0,32)
    int mrow = m0 + w * 16 + (lane >> 4) * 4;
#pragma unroll
    for (int r = 0; r < 4; ++r) {
      int m = mrow + r;
      int t = m >> 6, b = m & 63;
      float v = acc[nt][r] + bias;
      size_t o = (((size_t)t * NB + nb8) * 64 + b) * 32 + slot;
      if constexpr (XF32) ((float*)xg_out)[o] = v;
      else                ((u16*)xg_out)[o] = f2bf(v);
    }
  }
}

// ---------------------------------------------------------------- scan
// 125 blocks x 256 threads. Block nb owns hidden cols [8nb, 8nb+8).
//
// h EXCHANGE via WRITE-ONCE RING + VERIFIED, LINE-SPACED FLAGS:
//  - Ring: 512 slots x (64 x 1024 bf16) = 64 MB. Slot t holds h(t).
//    Write-once -> consumers use PLAIN CACHED 16B loads (L2-shared per XCD).
//  - Producer: astore64 (L2-bypass) h(t+1) into slot t+1; each storing
//    thread readback-verifies its own u64 (r2 showed store-ack != L3
//    visibility). Then tid0 publishes flag[nb] = t+1.
//  - Flags are 64-B SPACED (one L3 line each). r4's dense u32 flags put a
//    whole 32-producer group in 2 lines -> ~500 waves x 64 lanes of atomic
//    polls serialized on 2 L3 slices (hotspot). Now: 32 lines/group, and
//    only lanes 0-31 poll (lanes 32-63 were redundant duplicates).
//  - Consumer: K range [0,1024) = 4 groups of 8 kc; group g produced by
//    blocks [32g, 32g+32). Wave w polls group w's flags, publishes
//    lready[w]=t in LDS; loads/MFMAs per group stream in as producers land.
template<bool XF32>
__global__ void __launch_bounds__(256, 1)
lstm_scan(const float* __restrict__ Whh, const float* __restrict__ c0,
          const void* __restrict__ xg_, u16* __restrict__ ring,
          float* __restrict__ out, u32* __restrict__ bar) {
  __shared__ float Sc[4][16][33];
  __shared__ __align__(8) u16 hs[64][8];
  __shared__ int lready[4];
  const int tid = threadIdx.x;
  const int lane = tid & 63;
  const int w = tid >> 6;
  const int nb = blockIdx.x;
  const int s = lane & 15;        // gate-row index within N-tile
  const int q = lane >> 4;        // k-quarter

  if (tid < 4) lready[tid] = 0;

  u32* flags = bar + 256;   // 64-B-spaced flags: flag[nb] at flags[nb*16]
  u64* ring64 = (u64*)ring;

  // ---- stage this lane's W_hh B-fragments for 2 N-tiles (once) ----
  bf16x8 wreg0[32], wreg1[32];
  {
    const int jj0 = s;
    const float* wrow0 =
        Whh + (size_t)((jj0 >> 3) * Hn + nb * 8 + (jj0 & 7)) * Hn;
    const int jj1 = 16 + s;
    const float* wrow1 =
        Whh + (size_t)((jj1 >> 3) * Hn + nb * 8 + (jj1 & 7)) * Hn;
#pragma unroll
    for (int kc = 0; kc < 32; ++kc) {
      const int k0 = kc * 32 + q * 8;
      bf16x8 v0, v1;
#pragma unroll
      for (int j = 0; j < 8; ++j) {
        float f0 = (k0 + j < Hn) ? wrow0[k0 + j] : 0.f;
        float f1 = (k0 + j < Hn) ? wrow1[k0 + j] : 0.f;
        v0[j] = (short)f2bf(f0);
        v1[j] = (short)f2bf(f1);
      }
      wreg0[kc] = v0;
      wreg1[kc] = v1;
    }
  }

  // elementwise lane mapping: 2 cells per lane: (batch-local bl+8k, col cc)
  const int bl = lane >> 3, cc = lane & 7;
  const int jh = nb * 8 + cc;
  float cst[2];
  cst[0] = c0[(size_t)(w * 16 + bl) * Hn + jh];
  cst[1] = c0[(size_t)(w * 16 + bl + 8) * Hn + jh];

  const float* xf = (const float*)xg_;
  const u16* xh = (const u16*)xg_;

  // prefetch xg for t=0
  float xa[8];
  {
    size_t base = (((size_t)0 * NB + nb) * 64 + w * 16 + q * 4) * 32 + s;
#pragma unroll
    for (int nt = 0; nt < 2; ++nt)
#pragma unroll
      for (int r = 0; r < 4; ++r) {
        size_t o = base + (size_t)r * 32 + nt * 16;
        xa[nt * 4 + r] = XF32 ? xf[o] : bf2f(xh[o]);
      }
  }

  // my flag line to poll (wave w polls producers of K-group w; lanes 0-31)
  int pidx = 32 * w + (lane & 31);
  if (pidx >= NB) pidx = NB - 1;
  const u32* pf = flags + (size_t)pidx * 16;

  __syncthreads();   // lready init visible

  for (int t = 0; t < Tn; ++t) {
    // slot t: consumer reads h(t) with plain cached loads
    const u16* hrow = ring + (size_t)t * (Bn * KP) +
                      (size_t)(w * 16 + s) * KP + q * 8;
    // slot t+1: producer writes h(t+1) (u64 view; row stride 256 u64)
    u64* hn = ring64 + (size_t)(t + 1) * (Bn * KP / 4);

    // ---- duty poll: wave w waits for group-w producers, publishes to LDS
    if (t > 0) {
      while (true) {
        u32 f = (lane < 32) ? aload32(pf) : 0xffffffffu;
        if (__all((int)(f >= (u32)t))) break;
        __builtin_amdgcn_s_sleep(1);
      }
      if (lane == 0)
        __hip_atomic_store(&lready[w], t, __ATOMIC_RELAXED,
                           __HIP_MEMORY_SCOPE_WORKGROUP);
    }

    auto wait_g = [&](int g) {
      if (g == w) return;
      while (__hip_atomic_load(&lready[g], __ATOMIC_RELAXED,
                               __HIP_MEMORY_SCOPE_WORKGROUP) < t) {
      }
      __builtin_amdgcn_sched_barrier(0);
    };
    auto load8 = [&](bf16x8* buf, int kcb) {
#pragma unroll
      for (int k = 0; k < 8; ++k)
        buf[k] = *(const bf16x8*)(hrow + (size_t)(kcb + k) * 32);
    };

    f32x4 a00 = {xa[0], xa[1], xa[2], xa[3]};
    f32x4 a01 = {0.f, 0.f, 0.f, 0.f};
    f32x4 a10 = {xa[4], xa[5], xa[6], xa[7]};
    f32x4 a11 = {0.f, 0.f, 0.f, 0.f};

    bf16x8 b0[8], b1[8];
    wait_g(0);
    load8(b0, 0);
    wait_g(1);
    load8(b1, 8);
#pragma unroll
    for (int k = 0; k < 8; ++k) {
      a00 = __builtin_amdgcn_mfma_f32_16x16x32_bf16(b0[k], wreg0[k], a00, 0, 0, 0);
      a10 = __builtin_amdgcn_mfma_f32_16x16x32_bf16(b0[k], wreg1[k], a10, 0, 0, 0);
    }
    wait_g(2);
    load8(b0, 16);
#pragma unroll
    for (int k = 0; k < 8; ++k) {
      a00 = __builtin_amdgcn_mfma_f32_16x16x32_bf16(b1[k], wreg0[8 + k], a00, 0, 0, 0);
      a10 = __builtin_amdgcn_mfma_f32_16x16x32_bf16(b1[k], wreg1[8 + k], a10, 0, 0, 0);
    }
    wait_g(3);
    load8(b1, 24);
#pragma unroll
    for (int k = 0; k < 8; ++k) {
      a01 = __builtin_amdgcn_mfma_f32_16x16x32_bf16(b0[k], wreg0[16 + k], a01, 0, 0, 0);
      a11 = __builtin_amdgcn_mfma_f32_16x16x32_bf16(b0[k], wreg1[16 + k], a11, 0, 0, 0);
    }
#pragma unroll
    for (int k = 0; k < 8; ++k) {
      a01 = __builtin_amdgcn_mfma_f32_16x16x32_bf16(b1[k], wreg0[24 + k], a01, 0, 0, 0);
      a11 = __builtin_amdgcn_mfma_f32_16x16x32_bf16(b1[k], wreg1[24 + k], a11, 0, 0, 0);
    }

    // redistribute C within the wave via LDS (writer wave == reader wave)
#pragma unroll
    for (int r = 0; r < 4; ++r) {
      Sc[w][q * 4 + r][s]      = a00[r] + a01[r];
      Sc[w][q * 4 + r][16 + s] = a10[r] + a11[r];
    }

    float hv[2];
#pragma unroll
    for (int k = 0; k < 2; ++k) {
      int bb = bl + 8 * k;
      float gi = Sc[w][bb][cc];
      float gf = Sc[w][bb][8 + cc];
      float gg = Sc[w][bb][16 + cc];
      float go = Sc[w][bb][24 + cc];
      float iv = sigm(gi), fv = sigm(gf), gv = tanh_f(gg), ov = sigm(go);
      cst[k] = fv * cst[k] + iv * gv;
      hv[k] = ov * tanh_f(cst[k]);
      out[((size_t)t * Bn + (w * 16 + bb)) * Hn + jh] = hv[k];  // cached store
      hs[w * 16 + bb][cc] = f2bf(hv[k]);                        // stage bf16
    }

    if (t != Tn - 1) {
      __syncthreads();                 // hs ready; block's MFMAs done
      if (tid < 128) {
        int row = tid >> 1, half = tid & 1;
        u64 hvv = *(const u64*)&hs[row][half * 4];   // 4 bf16 packed
        u64* ad = hn + (size_t)row * 256 + nb * 2 + half;
        astore64(ad, hvv);
        // small backoff so the store has traversed to L3 before the first
        // readback attempt (avoids 1-2 wasted retry round trips)
        __builtin_amdgcn_s_sleep(2);
        // readback-verify: loop until the bypass load returns what we
        // stored -> data is physically at the coherent point.
        while (aload64(ad) != hvv) __builtin_amdgcn_s_sleep(1);
      }
      __syncthreads();                 // all 128 stores verified at L3
      if (tid == 0) astore32(flags + (size_t)nb * 16, (u32)(t + 1));

      // next-step xg prefetch (normal cached loads, overlaps next poll)
      {
        size_t base =
            (((size_t)(t + 1) * NB + nb) * 64 + w * 16 + q * 4) * 32 + s;
#pragma unroll
        for (int nt = 0; nt < 2; ++nt)
#pragma unroll
          for (int r = 0; r < 4; ++r) {
            size_t o = base + (size_t)r * 32 + nt * 16;
            xa[nt * 4 + r] = XF32 ? xf[o] : bf2f(xh[o]);
          }
      }
    }
  }
}

// ---------------------------------------------------------------- launch
extern "C" void kernel_launch(void* const* d_in, const int* in_sizes, int n_in,
                              void* d_out, int out_size, void* d_ws, size_t ws_size,
                              hipStream_t stream) {
  const float* inputs = (const float*)d_in[0];
  const float* h0 = (const float*)d_in[1];
  const float* c0 = (const float*)d_in[2];
  const float* W_ih = (const float*)d_in[3];
  const float* W_hh = (const float*)d_in[4];
  const float* b_ih = (const float*)d_in[5];
  const float* b_hh = (const float*)d_in[6];
  float* out = (float*)d_out;

  char* ws = (char*)d_ws;
  size_t off = 0;
  auto carve = [&](size_t bytes) {
    char* p = ws + off;
    off = (off + bytes + 255) & ~(size_t)255;
    return p;
  };
  u32* bar = (u32*)carve(16384);
  u16* in_bf = (u16*)carve((size_t)Tn * Bn * KI * 2);
  u16* wih_bf = (u16*)carve((size_t)G4H * KI * 2);
  u16* ring = (u16*)carve((size_t)Tn * Bn * KP * 2);   // 64 MB write-once ring
  size_t fixed = off;
  size_t xg_f32 = (size_t)Tn * NB * 64 * 32 * 4;
  bool xf32 = (ws_size >= fixed + xg_f32);
  void* xg = (void*)carve(xf32 ? xg_f32 : xg_f32 / 2);

  int tot_in = Tn * Bn * KI;
  conv_pad<<<dim3((tot_in + 255) / 256), dim3(256), 0, stream>>>(
      inputs, in_bf, Tn * Bn, In, KI);
  int tot_w = G4H * KI;
  conv_pad<<<dim3((tot_w + 255) / 256), dim3(256), 0, stream>>>(
      W_ih, wih_bf, G4H, In, KI);
  init_scan<<<dim3(512), dim3(256), 0, stream>>>(h0, ring, bar);

  if (xf32) {
    gemm_xg<true><<<dim3(Tn * Bn / 64, (G4H + 63) / 64), dim3(256), 0, stream>>>(
        in_bf, wih_bf, b_ih, b_hh, xg);
    lstm_scan<true><<<dim3(NB), dim3(256), 0, stream>>>(
        W_hh, c0, xg, ring, out, bar);
  } else {
    gemm_xg<false><<<dim3(Tn * Bn / 64, (G4H + 63) / 64), dim3(256), 0, stream>>>(
        in_bf, wih_bf, b_ih, b_hh, xg);
    lstm_scan<false><<<dim3(NB), dim3(256), 0, stream>>>(
        W_hh, c0, xg, ring, out, bar);
  }
}